// Round 3
// baseline (116.731 us; speedup 1.0000x reference)
//
#include <hip/hip_runtime.h>
#include <hip/hip_bf16.h>

#define GRP   8
#define PCH   64
#define FO    256
#define CIN   512
#define PTILE 16

typedef __attribute__((ext_vector_type(8))) short bf16x8;
typedef __attribute__((ext_vector_type(4))) float f32x4;

__device__ __forceinline__ short f2b(float f) {
    __hip_bfloat16 h = __float2bfloat16(f);
    short s;
    __builtin_memcpy(&s, &h, 2);
    return s;
}
__device__ __forceinline__ float sigmoidf_(float b) {
    return 1.0f / (1.0f + __expf(-b));
}
__device__ __forceinline__ float dot4(f32x4 a, f32x4 b) {
    return fmaf(a[0], b[0], fmaf(a[1], b[1], fmaf(a[2], b[2], a[3] * b[3])));
}

// ---- pre-kernel: repack kernels fp32 [g][p][f] -> bf16 MFMA A-frag order ----
// wpk[(((g*16+t)*2+kb)*64+lane)*8+j] = w[g][ p=kb*32+(lane>>4)*8+j ][ f=t*16+(lane&15) ]
__global__ void repack_w(const float* __restrict__ wk, unsigned short* __restrict__ wpk) {
    int id = blockIdx.x * 256 + threadIdx.x;      // 0 .. 131071
    int j    = id & 7;
    int lane = (id >> 3) & 63;
    int kb   = (id >> 9) & 1;
    int t    = (id >> 10) & 15;
    int g    = id >> 14;
    int p = kb * 32 + (lane >> 4) * 8 + j;
    int f = t * 16 + (lane & 15);
    unsigned short u;
    __hip_bfloat16 h = __float2bfloat16(wk[(g * PCH + p) * FO + f]);
    __builtin_memcpy(&u, &h, 2);
    wpk[id] = u;
}

__global__ __launch_bounds__(512, 4)
void dynroute_reg(const float* __restrict__ x, const unsigned short* __restrict__ wpk,
                  const float* __restrict__ bias, float* __restrict__ out) {
    __shared__ float part_s[8][PTILE][8];     // [wave][pos][g] partial dots, 4 KB
    __shared__ float alpha1_s[PTILE][8];
    __shared__ float alpha2_s[PTILE][8];

    const int tid  = threadIdx.x;
    const int lane = tid & 63;
    const int wave = tid >> 6;                // 0..7, owns f-tiles t = wave*2 + {0,1}
    const int pos  = lane & 15;
    const int lq   = lane >> 4;               // 0..3
    const long m0  = (long)blockIdx.x * PTILE;

    // bias for this lane's two f-quads (f = (wave*2+tt)*16 + lq*4 + r)
    const float4 bias0 = *reinterpret_cast<const float4*>(bias + (wave * 2 + 0) * 16 + lq * 4);
    const float4 bias1 = *reinterpret_cast<const float4*>(bias + (wave * 2 + 1) * 16 + lq * 4);

    // ---------------- Phase 1: grouped GEMM via MFMA, con stays in VGPRs ----
    f32x4 acc[GRP][2];
    const float* xb = x + (m0 + pos) * CIN + lq * 8;
    #pragma unroll
    for (int g = 0; g < GRP; ++g) {
        const float4 a0 = *reinterpret_cast<const float4*>(xb + g * PCH);
        const float4 a1 = *reinterpret_cast<const float4*>(xb + g * PCH + 4);
        const float4 b0 = *reinterpret_cast<const float4*>(xb + g * PCH + 32);
        const float4 b1 = *reinterpret_cast<const float4*>(xb + g * PCH + 36);
        bf16x8 xf0, xf1;
        xf0[0] = f2b(a0.x); xf0[1] = f2b(a0.y); xf0[2] = f2b(a0.z); xf0[3] = f2b(a0.w);
        xf0[4] = f2b(a1.x); xf0[5] = f2b(a1.y); xf0[6] = f2b(a1.z); xf0[7] = f2b(a1.w);
        xf1[0] = f2b(b0.x); xf1[1] = f2b(b0.y); xf1[2] = f2b(b0.z); xf1[3] = f2b(b0.w);
        xf1[4] = f2b(b1.x); xf1[5] = f2b(b1.y); xf1[6] = f2b(b1.z); xf1[7] = f2b(b1.w);
        #pragma unroll
        for (int tt = 0; tt < 2; ++tt) {
            const int t = wave * 2 + tt;
            const bf16x8 wf0 = *reinterpret_cast<const bf16x8*>(
                wpk + ((((g * 16 + t) * 2 + 0) * 64 + lane) << 3));
            const bf16x8 wf1 = *reinterpret_cast<const bf16x8*>(
                wpk + ((((g * 16 + t) * 2 + 1) * 64 + lane) << 3));
            f32x4 a = {0.f, 0.f, 0.f, 0.f};
            a = __builtin_amdgcn_mfma_f32_16x16x32_bf16(wf0, xf0, a, 0, 0, 0);
            a = __builtin_amdgcn_mfma_f32_16x16x32_bf16(wf1, xf1, a, 0, 0, 0);
            acc[g][tt] = a;   // lane holds con[pos][f = t*16 + lq*4 + r]
        }
    }

    // ---------------- Phase 2: routing via S-trick, all lane-local ---------
    // S = sum_g con_g  (this lane's 8 f-slice)
    f32x4 s0 = acc[0][0], s1 = acc[0][1];
    #pragma unroll
    for (int g = 1; g < GRP; ++g) { s0 += acc[g][0]; s1 += acc[g][1]; }

    // d1[g] = partial <con_g, S> over this lane's f's
    float d1[GRP];
    #pragma unroll
    for (int g = 0; g < GRP; ++g)
        d1[g] = dot4(acc[g][0], s0) + dot4(acc[g][1], s1);
    #pragma unroll
    for (int g = 0; g < GRP; ++g) {
        d1[g] += __shfl_xor(d1[g], 16, 64);
        d1[g] += __shfl_xor(d1[g], 32, 64);
    }
    if (lq == 0) {   // lanes 0..15 of each wave: write per-wave partials
        float4 v0 = {d1[0], d1[1], d1[2], d1[3]};
        float4 v1 = {d1[4], d1[5], d1[6], d1[7]};
        *reinterpret_cast<float4*>(&part_s[wave][pos][0]) = v0;
        *reinterpret_cast<float4*>(&part_s[wave][pos][4]) = v1;
    }
    __syncthreads();

    float b1r = 0.f;   // kept by reducer lanes for beta2
    if (tid < 128) {   // lane handles (pos=tid>>3, g=tid&7)
        const int rp = tid >> 3, rg = tid & 7;
        float s = 0.f;
        #pragma unroll
        for (int w = 0; w < 8; ++w) s += part_s[w][rp][rg];
        b1r = 0.5f * s;
        alpha1_s[rp][rg] = sigmoidf_(b1r);
    }
    __syncthreads();

    // Salpha = sum_g alpha1[g] * con_g
    float a1v[GRP];
    #pragma unroll
    for (int g = 0; g < GRP; ++g) a1v[g] = alpha1_s[pos][g];
    f32x4 sa0 = acc[0][0] * a1v[0], sa1 = acc[0][1] * a1v[0];
    #pragma unroll
    for (int g = 1; g < GRP; ++g) {
        sa0 = a1v[g] * acc[g][0] + sa0;
        sa1 = a1v[g] * acc[g][1] + sa1;
    }
    float d2[GRP];
    #pragma unroll
    for (int g = 0; g < GRP; ++g)
        d2[g] = dot4(acc[g][0], sa0) + dot4(acc[g][1], sa1);
    #pragma unroll
    for (int g = 0; g < GRP; ++g) {
        d2[g] += __shfl_xor(d2[g], 16, 64);
        d2[g] += __shfl_xor(d2[g], 32, 64);
    }
    if (lq == 0) {
        float4 v0 = {d2[0], d2[1], d2[2], d2[3]};
        float4 v1 = {d2[4], d2[5], d2[6], d2[7]};
        *reinterpret_cast<float4*>(&part_s[wave][pos][0]) = v0;
        *reinterpret_cast<float4*>(&part_s[wave][pos][4]) = v1;
    }
    __syncthreads();

    if (tid < 128) {
        const int rp = tid >> 3, rg = tid & 7;
        float s = 0.f;
        #pragma unroll
        for (int w = 0; w < 8; ++w) s += part_s[w][rp][rg];
        alpha2_s[rp][rg] = sigmoidf_(b1r + s);
    }
    __syncthreads();

    // ---------------- Phase 3: out = sum_g alpha2[g]*con_g + bias ----------
    float a2v[GRP];
    #pragma unroll
    for (int g = 0; g < GRP; ++g) a2v[g] = alpha2_s[pos][g];
    f32x4 o0 = {bias0.x, bias0.y, bias0.z, bias0.w};
    f32x4 o1 = {bias1.x, bias1.y, bias1.z, bias1.w};
    #pragma unroll
    for (int g = 0; g < GRP; ++g) {
        o0 = a2v[g] * acc[g][0] + o0;
        o1 = a2v[g] * acc[g][1] + o1;
    }
    float* ob = out + (m0 + pos) * FO + lq * 4;
    *reinterpret_cast<float4*>(ob + (wave * 2 + 0) * 16) = *reinterpret_cast<float4*>(&o0);
    *reinterpret_cast<float4*>(ob + (wave * 2 + 1) * 16) = *reinterpret_cast<float4*>(&o1);
}

extern "C" void kernel_launch(void* const* d_in, const int* in_sizes, int n_in,
                              void* d_out, int out_size, void* d_ws, size_t ws_size,
                              hipStream_t stream) {
    const float* x    = (const float*)d_in[0];
    const float* wk   = (const float*)d_in[1];
    const float* bias = (const float*)d_in[2];
    float* out        = (float*)d_out;
    unsigned short* wpk = (unsigned short*)d_ws;   // 256 KB of workspace

    hipLaunchKernelGGL(repack_w, dim3(512), dim3(256), 0, stream, wk, wpk);

    const int M = in_sizes[0] / CIN;               // 25088
    hipLaunchKernelGGL(dynroute_reg, dim3(M / PTILE), dim3(512), 0, stream,
                       x, wpk, bias, out);
}

// Round 4
// 89.051 us; speedup vs baseline: 1.3108x; 1.3108x over previous
//
#include <hip/hip_runtime.h>
#include <hip/hip_bf16.h>

#define GRP   8
#define PCH   64
#define FO    256
#define CIN   512
#define PTILE 16

typedef __attribute__((ext_vector_type(8))) short bf16x8;
typedef __attribute__((ext_vector_type(4))) float f32x4;

__device__ __forceinline__ short f2b(float f) {
    __hip_bfloat16 h = __float2bfloat16(f);
    short s;
    __builtin_memcpy(&s, &h, 2);
    return s;
}
__device__ __forceinline__ float sigmoidf_(float b) {
    return 1.0f / (1.0f + __expf(-b));
}
__device__ __forceinline__ float dot4(f32x4 a, f32x4 b) {
    return fmaf(a[0], b[0], fmaf(a[1], b[1], fmaf(a[2], b[2], a[3] * b[3])));
}

// ---- pre-kernel: repack kernels fp32 [g][p][f] -> bf16 MFMA A-frag order ----
// wpk[(((g*16+t)*2+kb)*64+lane)*8+j] = w[g][ p=kb*32+(lane>>4)*8+j ][ f=t*16+(lane&15) ]
__global__ void repack_w(const float* __restrict__ wk, unsigned short* __restrict__ wpk) {
    int id = blockIdx.x * 256 + threadIdx.x;      // 0 .. 131071
    int j    = id & 7;
    int lane = (id >> 3) & 63;
    int kb   = (id >> 9) & 1;
    int t    = (id >> 10) & 15;
    int g    = id >> 14;
    int p = kb * 32 + (lane >> 4) * 8 + j;
    int f = t * 16 + (lane & 15);
    unsigned short u;
    __hip_bfloat16 h = __float2bfloat16(wk[(g * PCH + p) * FO + f]);
    __builtin_memcpy(&u, &h, 2);
    wpk[id] = u;
}

__global__ __launch_bounds__(512, 1)
void dynroute_reg(const float* __restrict__ x, const unsigned short* __restrict__ wpk,
                  const float* __restrict__ bias, float* __restrict__ out) {
    __shared__ float part_s[8][PTILE][8];     // [wave][pos][g] partial dots, 4 KB
    __shared__ float alpha1_s[PTILE][8];
    __shared__ float alpha2_s[PTILE][8];

    const int tid  = threadIdx.x;
    const int lane = tid & 63;
    const int wave = tid >> 6;                // 0..7, owns f-tiles t = wave*2 + {0,1}
    const int pos  = lane & 15;
    const int lq   = lane >> 4;               // 0..3
    const long m0  = (long)blockIdx.x * PTILE;

    // ---------------- Phase 1: grouped GEMM via MFMA, con stays in VGPRs ----
    f32x4 acc[GRP][2];
    const float* xb = x + (m0 + pos) * CIN + lq * 8;
    #pragma unroll
    for (int g = 0; g < GRP; ++g) {
        const float4 a0 = *reinterpret_cast<const float4*>(xb + g * PCH);
        const float4 a1 = *reinterpret_cast<const float4*>(xb + g * PCH + 4);
        const float4 b0 = *reinterpret_cast<const float4*>(xb + g * PCH + 32);
        const float4 b1 = *reinterpret_cast<const float4*>(xb + g * PCH + 36);
        bf16x8 xf0, xf1;
        xf0[0] = f2b(a0.x); xf0[1] = f2b(a0.y); xf0[2] = f2b(a0.z); xf0[3] = f2b(a0.w);
        xf0[4] = f2b(a1.x); xf0[5] = f2b(a1.y); xf0[6] = f2b(a1.z); xf0[7] = f2b(a1.w);
        xf1[0] = f2b(b0.x); xf1[1] = f2b(b0.y); xf1[2] = f2b(b0.z); xf1[3] = f2b(b0.w);
        xf1[4] = f2b(b1.x); xf1[5] = f2b(b1.y); xf1[6] = f2b(b1.z); xf1[7] = f2b(b1.w);
        #pragma unroll
        for (int tt = 0; tt < 2; ++tt) {
            const int t = wave * 2 + tt;
            const bf16x8 wf0 = *reinterpret_cast<const bf16x8*>(
                wpk + ((((g * 16 + t) * 2 + 0) * 64 + lane) << 3));
            const bf16x8 wf1 = *reinterpret_cast<const bf16x8*>(
                wpk + ((((g * 16 + t) * 2 + 1) * 64 + lane) << 3));
            f32x4 a = {0.f, 0.f, 0.f, 0.f};
            a = __builtin_amdgcn_mfma_f32_16x16x32_bf16(wf0, xf0, a, 0, 0, 0);
            a = __builtin_amdgcn_mfma_f32_16x16x32_bf16(wf1, xf1, a, 0, 0, 0);
            acc[g][tt] = a;   // lane holds con[pos][f = t*16 + lq*4 + r]
        }
    }

    // ---------------- Phase 2: routing via S-trick, all lane-local ---------
    // S = sum_g con_g  (this lane's 8 f-slice)
    f32x4 s0 = acc[0][0], s1 = acc[0][1];
    #pragma unroll
    for (int g = 1; g < GRP; ++g) { s0 += acc[g][0]; s1 += acc[g][1]; }

    // d1[g] = partial <con_g, S> over this lane's f's
    float d1[GRP];
    #pragma unroll
    for (int g = 0; g < GRP; ++g)
        d1[g] = dot4(acc[g][0], s0) + dot4(acc[g][1], s1);
    #pragma unroll
    for (int g = 0; g < GRP; ++g) {
        d1[g] += __shfl_xor(d1[g], 16, 64);
        d1[g] += __shfl_xor(d1[g], 32, 64);
    }
    if (lq == 0) {   // lanes 0..15 of each wave: write per-wave partials
        float4 v0 = {d1[0], d1[1], d1[2], d1[3]};
        float4 v1 = {d1[4], d1[5], d1[6], d1[7]};
        *reinterpret_cast<float4*>(&part_s[wave][pos][0]) = v0;
        *reinterpret_cast<float4*>(&part_s[wave][pos][4]) = v1;
    }
    __syncthreads();

    float b1r = 0.f;   // kept by reducer lanes for beta2
    if (tid < 128) {   // lane handles (pos=tid>>3, g=tid&7)
        const int rp = tid >> 3, rg = tid & 7;
        float s = 0.f;
        #pragma unroll
        for (int w = 0; w < 8; ++w) s += part_s[w][rp][rg];
        b1r = 0.5f * s;
        alpha1_s[rp][rg] = sigmoidf_(b1r);
    }
    __syncthreads();

    // Salpha = sum_g alpha1[g] * con_g
    float a1v[GRP];
    #pragma unroll
    for (int g = 0; g < GRP; ++g) a1v[g] = alpha1_s[pos][g];
    f32x4 sa0 = acc[0][0] * a1v[0], sa1 = acc[0][1] * a1v[0];
    #pragma unroll
    for (int g = 1; g < GRP; ++g) {
        sa0 = a1v[g] * acc[g][0] + sa0;
        sa1 = a1v[g] * acc[g][1] + sa1;
    }
    float d2[GRP];
    #pragma unroll
    for (int g = 0; g < GRP; ++g)
        d2[g] = dot4(acc[g][0], sa0) + dot4(acc[g][1], sa1);
    #pragma unroll
    for (int g = 0; g < GRP; ++g) {
        d2[g] += __shfl_xor(d2[g], 16, 64);
        d2[g] += __shfl_xor(d2[g], 32, 64);
    }
    if (lq == 0) {
        float4 v0 = {d2[0], d2[1], d2[2], d2[3]};
        float4 v1 = {d2[4], d2[5], d2[6], d2[7]};
        *reinterpret_cast<float4*>(&part_s[wave][pos][0]) = v0;
        *reinterpret_cast<float4*>(&part_s[wave][pos][4]) = v1;
    }
    __syncthreads();

    if (tid < 128) {
        const int rp = tid >> 3, rg = tid & 7;
        float s = 0.f;
        #pragma unroll
        for (int w = 0; w < 8; ++w) s += part_s[w][rp][rg];
        alpha2_s[rp][rg] = sigmoidf_(b1r + s);
    }
    __syncthreads();

    // ---------------- Phase 3: out = sum_g alpha2[g]*con_g + bias ----------
    float a2v[GRP];
    #pragma unroll
    for (int g = 0; g < GRP; ++g) a2v[g] = alpha2_s[pos][g];
    const float4 bias0 = *reinterpret_cast<const float4*>(bias + (wave * 2 + 0) * 16 + lq * 4);
    const float4 bias1 = *reinterpret_cast<const float4*>(bias + (wave * 2 + 1) * 16 + lq * 4);
    f32x4 o0 = {bias0.x, bias0.y, bias0.z, bias0.w};
    f32x4 o1 = {bias1.x, bias1.y, bias1.z, bias1.w};
    #pragma unroll
    for (int g = 0; g < GRP; ++g) {
        o0 = a2v[g] * acc[g][0] + o0;
        o1 = a2v[g] * acc[g][1] + o1;
    }
    float* ob = out + (m0 + pos) * FO + lq * 4;
    *reinterpret_cast<float4*>(ob + (wave * 2 + 0) * 16) = *reinterpret_cast<float4*>(&o0);
    *reinterpret_cast<float4*>(ob + (wave * 2 + 1) * 16) = *reinterpret_cast<float4*>(&o1);
}

extern "C" void kernel_launch(void* const* d_in, const int* in_sizes, int n_in,
                              void* d_out, int out_size, void* d_ws, size_t ws_size,
                              hipStream_t stream) {
    const float* x    = (const float*)d_in[0];
    const float* wk   = (const float*)d_in[1];
    const float* bias = (const float*)d_in[2];
    float* out        = (float*)d_out;
    unsigned short* wpk = (unsigned short*)d_ws;   // 256 KB of workspace

    hipLaunchKernelGGL(repack_w, dim3(512), dim3(256), 0, stream, wk, wpk);

    const int M = in_sizes[0] / CIN;               // 25088
    hipLaunchKernelGGL(dynroute_reg, dim3(M / PTILE), dim3(512), 0, stream,
                       x, wpk, bias, out);
}

// Round 5
// 51.028 us; speedup vs baseline: 2.2876x; 1.7451x over previous
//
#include <hip/hip_runtime.h>
#include <hip/hip_bf16.h>

#define GRP   8
#define PCH   64
#define FO    256
#define CIN   512
#define PTILE 16
#define XROW  520          // u16 per staged x row (512 + 8 pad)

typedef __attribute__((ext_vector_type(8))) short bf16x8;
typedef __attribute__((ext_vector_type(4))) float f32x4;

__device__ __forceinline__ short f2b(float f) {
    __hip_bfloat16 h = __float2bfloat16(f);
    short s;
    __builtin_memcpy(&s, &h, 2);
    return s;
}
__device__ __forceinline__ float sigmoidf_(float b) {
    return 1.0f / (1.0f + __expf(-b));
}
__device__ __forceinline__ float dot4(f32x4 a, f32x4 b) {
    return fmaf(a[0], b[0], fmaf(a[1], b[1], fmaf(a[2], b[2], a[3] * b[3])));
}

// ---- pre-kernel: repack kernels fp32 [g][p][f] -> bf16 MFMA A-frag order ----
// wpk[(((g*16+t)*2+kb)*64+lane)*8+j] = w[g][ p=kb*32+(lane>>4)*8+j ][ f=t*16+(lane&15) ]
__global__ void repack_w(const float* __restrict__ wk, unsigned short* __restrict__ wpk) {
    int id = blockIdx.x * 256 + threadIdx.x;      // 0 .. 131071
    int j    = id & 7;
    int lane = (id >> 3) & 63;
    int kb   = (id >> 9) & 1;
    int t    = (id >> 10) & 15;
    int g    = id >> 14;
    int p = kb * 32 + (lane >> 4) * 8 + j;
    int f = t * 16 + (lane & 15);
    unsigned short u;
    __hip_bfloat16 h = __float2bfloat16(wk[(g * PCH + p) * FO + f]);
    __builtin_memcpy(&u, &h, 2);
    wpk[id] = u;
}

__global__ __launch_bounds__(1024, 1)
void dynroute_reg(const float* __restrict__ x, const unsigned short* __restrict__ wpk,
                  const float* __restrict__ bias, float* __restrict__ out) {
    __shared__ unsigned short xs[PTILE * XROW];   // 16.25 KB, bf16 x tile
    __shared__ float part_s[16][PTILE][8];        // [wave][pos][g], 8 KB
    __shared__ float alpha1_s[PTILE][8];
    __shared__ float alpha2_s[PTILE][8];

    const int tid  = threadIdx.x;
    const int lane = tid & 63;
    const int wave = tid >> 6;                // 0..15 == f-tile t
    const int pos  = lane & 15;
    const int lq   = lane >> 4;               // 0..3
    const long m0  = (long)blockIdx.x * PTILE;

    // ---------------- Stage x tile -> LDS as bf16 (convert once) -----------
    {
        const int srow = wave;                // wave w stages row w (coalesced 2 KB)
        const int scol = (lane) * 8;          // f32 col 0..511 step 8
        const float* xp = x + (m0 + srow) * CIN + scol;
        const float4 u0 = *reinterpret_cast<const float4*>(xp);
        const float4 u1 = *reinterpret_cast<const float4*>(xp + 4);
        bf16x8 v;
        v[0] = f2b(u0.x); v[1] = f2b(u0.y); v[2] = f2b(u0.z); v[3] = f2b(u0.w);
        v[4] = f2b(u1.x); v[5] = f2b(u1.y); v[6] = f2b(u1.z); v[7] = f2b(u1.w);
        *reinterpret_cast<bf16x8*>(&xs[srow * XROW + scol]) = v;
    }
    __syncthreads();

    // ---------------- Phase 1: grouped GEMM via MFMA, con in VGPRs ---------
    // wave t computes con[pos][f = t*16 + lq*4 + r] for all 8 g
    f32x4 acc[GRP];
    {
        const unsigned short* xrow = &xs[pos * XROW];
        #pragma unroll
        for (int g = 0; g < GRP; ++g) {
            const bf16x8 xf0 = *reinterpret_cast<const bf16x8*>(&xrow[g * 64 + lq * 8]);
            const bf16x8 xf1 = *reinterpret_cast<const bf16x8*>(&xrow[g * 64 + 32 + lq * 8]);
            const bf16x8 wf0 = *reinterpret_cast<const bf16x8*>(
                wpk + ((((g * 16 + wave) * 2 + 0) * 64 + lane) << 3));
            const bf16x8 wf1 = *reinterpret_cast<const bf16x8*>(
                wpk + ((((g * 16 + wave) * 2 + 1) * 64 + lane) << 3));
            f32x4 a = {0.f, 0.f, 0.f, 0.f};
            a = __builtin_amdgcn_mfma_f32_16x16x32_bf16(wf0, xf0, a, 0, 0, 0);
            a = __builtin_amdgcn_mfma_f32_16x16x32_bf16(wf1, xf1, a, 0, 0, 0);
            acc[g] = a;
        }
    }

    // ---------------- Phase 2: routing via S-trick -------------------------
    // S = sum_g con_g (this lane's 4-f slice)
    f32x4 s0 = acc[0];
    #pragma unroll
    for (int g = 1; g < GRP; ++g) s0 += acc[g];

    float d1[GRP];
    #pragma unroll
    for (int g = 0; g < GRP; ++g) d1[g] = dot4(acc[g], s0);
    #pragma unroll
    for (int g = 0; g < GRP; ++g) {
        d1[g] += __shfl_xor(d1[g], 16, 64);
        d1[g] += __shfl_xor(d1[g], 32, 64);
    }
    if (lq == 0) {
        float4 v0 = {d1[0], d1[1], d1[2], d1[3]};
        float4 v1 = {d1[4], d1[5], d1[6], d1[7]};
        *reinterpret_cast<float4*>(&part_s[wave][pos][0]) = v0;
        *reinterpret_cast<float4*>(&part_s[wave][pos][4]) = v1;
    }
    __syncthreads();

    float b1r = 0.f;
    if (tid < 128) {       // thread handles (pos = tid>>3, g = tid&7)
        const int rp = tid >> 3, rg = tid & 7;
        float s = 0.f;
        #pragma unroll
        for (int w = 0; w < 16; ++w) s += part_s[w][rp][rg];
        b1r = 0.5f * s;
        alpha1_s[rp][rg] = sigmoidf_(b1r);
    }
    __syncthreads();

    // Salpha = sum_g alpha1[g] * con_g
    float a1v[GRP];
    #pragma unroll
    for (int g = 0; g < GRP; ++g) a1v[g] = alpha1_s[pos][g];
    f32x4 sa0 = acc[0] * a1v[0];
    #pragma unroll
    for (int g = 1; g < GRP; ++g) sa0 = a1v[g] * acc[g] + sa0;

    float d2[GRP];
    #pragma unroll
    for (int g = 0; g < GRP; ++g) d2[g] = dot4(acc[g], sa0);
    #pragma unroll
    for (int g = 0; g < GRP; ++g) {
        d2[g] += __shfl_xor(d2[g], 16, 64);
        d2[g] += __shfl_xor(d2[g], 32, 64);
    }
    if (lq == 0) {
        float4 v0 = {d2[0], d2[1], d2[2], d2[3]};
        float4 v1 = {d2[4], d2[5], d2[6], d2[7]};
        *reinterpret_cast<float4*>(&part_s[wave][pos][0]) = v0;
        *reinterpret_cast<float4*>(&part_s[wave][pos][4]) = v1;
    }
    __syncthreads();

    if (tid < 128) {
        const int rp = tid >> 3, rg = tid & 7;
        float s = 0.f;
        #pragma unroll
        for (int w = 0; w < 16; ++w) s += part_s[w][rp][rg];
        alpha2_s[rp][rg] = sigmoidf_(b1r + s);
    }
    __syncthreads();

    // ---------------- Phase 3: out = sum_g alpha2[g]*con_g + bias ----------
    float a2v[GRP];
    #pragma unroll
    for (int g = 0; g < GRP; ++g) a2v[g] = alpha2_s[pos][g];
    const float4 bb = *reinterpret_cast<const float4*>(bias + wave * 16 + lq * 4);
    f32x4 o0 = {bb.x, bb.y, bb.z, bb.w};
    #pragma unroll
    for (int g = 0; g < GRP; ++g) o0 = a2v[g] * acc[g] + o0;

    *reinterpret_cast<float4*>(out + (m0 + pos) * FO + wave * 16 + lq * 4) =
        *reinterpret_cast<float4*>(&o0);
}

extern "C" void kernel_launch(void* const* d_in, const int* in_sizes, int n_in,
                              void* d_out, int out_size, void* d_ws, size_t ws_size,
                              hipStream_t stream) {
    const float* x    = (const float*)d_in[0];
    const float* wk   = (const float*)d_in[1];
    const float* bias = (const float*)d_in[2];
    float* out        = (float*)d_out;
    unsigned short* wpk = (unsigned short*)d_ws;   // 256 KB of workspace

    hipLaunchKernelGGL(repack_w, dim3(512), dim3(256), 0, stream, wk, wpk);

    const int M = in_sizes[0] / CIN;               // 25088
    hipLaunchKernelGGL(dynroute_reg, dim3(M / PTILE), dim3(1024), 0, stream,
                       x, wpk, bias, out);
}